// Round 6
// baseline (124.424 us; speedup 1.0000x reference)
//
#include <hip/hip_runtime.h>
#include <stdint.h>

// ---------------------------------------------------------------------------
// LinearBlock: out[b, p*8+o] = clip((sum_{q,i} Wq[p,q,o,i]*xq[b,q*8+i])^2, 0, 6)
// Exact int8 path:
//   xq = xu/255,        xu = round(clip(x,0,1)*255)       in [0,255]
//   wq = wi*2/127,      wi = round(clip(w,-2,2)*63.5)     in [-127,127]
//   dot = (sum xu*wi) * 2/(255*127);  A zero-point: xs=xu-128, +128*rowsum[n].
//
// Round 6: 256x128 tile, BK=64, 256 threads (4 waves, 2Mx2N, wave 128x64),
// 3-buffer LDS ring (72 KB) -> 2 BLOCKS/CU so LDS and matrix pipes overlap
// ACROSS independently-synchronized blocks (rounds 2-5 all ran 1 block/CU in
// CU-wide-lockstep phases: LDS and MFMA serialized; invariant ~96-106 us).
// Counted vmcnt(6) (never 0 in loop); lgkm-counted ds_read/MFMA interleave;
// XOR chunk swizzle both-sides; XCD block swizzle.
// ---------------------------------------------------------------------------

typedef int i32x4 __attribute__((ext_vector_type(4)));

#define B_DIM   16384
#define IN_DIM  2048
#define OUT_DIM 2048

#define BM 256
#define BN 128
#define BK 64
#define KTILES (IN_DIM / BK)   // 32
#define ATILE  (BM * BK)       // 16384 bytes
#define BTILE  (BN * BK)       // 8192 bytes
#define BUFB   (ATILE + BTILE) // 24576 bytes

__device__ __forceinline__ void async16(const void* g, void* l) {
    __builtin_amdgcn_global_load_lds(
        (const __attribute__((address_space(1))) void*)g,
        (__attribute__((address_space(3))) void*)l, 16, 0, 0);
}

// --- quantize x: float [B,IN] -> int8 (value-128) [B,IN], 16 elems/thread ---
__global__ __launch_bounds__(256) void quant_x_kernel(const float* __restrict__ x,
                                                      int8_t* __restrict__ xq) {
    int i = blockIdx.x * 256 + threadIdx.x;           // 16-elem chunk id
    const float4* xv = (const float4*)x + (size_t)i * 4;
    union { int8_t c[16]; i32x4 v; } u;
#pragma unroll
    for (int j = 0; j < 4; ++j) {
        float4 v = xv[j];
        float f[4] = {v.x, v.y, v.z, v.w};
#pragma unroll
        for (int e = 0; e < 4; ++e) {
            float c = fminf(fmaxf(f[e], 0.0f), 1.0f);
            int q = (int)rintf(c * 255.0f) - 128;
            u.c[j * 4 + e] = (int8_t)q;
        }
    }
    *((i32x4*)xq + i) = u.v;
}

// --- quantize + relayout weight: [P=256,Q=256,8,8] f32 -> [2048][2048] int8
__global__ __launch_bounds__(256) void quant_w_kernel(const float* __restrict__ w,
                                                      int8_t* __restrict__ wq,
                                                      int* __restrict__ rowsum) {
    int p = blockIdx.x;          // 0..255
    int t = threadIdx.x;         // 0..255
    const float* wp = w + (size_t)p * 16384;
    int n = p * 8 + (t & 7);
    int lsum = 0;
#pragma unroll
    for (int s = 0; s < 8; ++s) {
        int g = t + s * 256;                     // 8-elem group id, 0..2047
        float4 v0 = *(const float4*)(wp + g * 8);
        float4 v1 = *(const float4*)(wp + g * 8 + 4);
        float f[8] = {v0.x, v0.y, v0.z, v0.w, v1.x, v1.y, v1.z, v1.w};
        union { int8_t c[8]; long long ll; } u;
#pragma unroll
        for (int e = 0; e < 8; ++e) {
            float c = fminf(fmaxf(f[e], -2.0f), 2.0f);
            int q = (int)rintf(c * 63.5f);       // == round((w/2)*127), exact
            u.c[e] = (int8_t)q;
            lsum += q;
        }
        int kg = g >> 3;
        *(long long*)(wq + (size_t)n * 2048 + kg * 8) = u.ll;
    }
    atomicAdd(&rowsum[n], lsum);
}

#define SB0 __builtin_amdgcn_sched_barrier(0)
#define BAR __builtin_amdgcn_s_barrier()
#define WLG(n) asm volatile("s_waitcnt lgkmcnt(" #n ")" ::: "memory")
#define WVM(n) asm volatile("s_waitcnt vmcnt(" #n ")" ::: "memory")

#define CL(mm)                                                                \
    _Pragma("unroll")                                                         \
    for (int n = 0; n < 4; ++n)                                               \
        acc[mm][n] = __builtin_amdgcn_mfma_i32_16x16x64_i8(af[mm], bf[n],     \
                                                           acc[mm][n], 0, 0, 0);

// One K-tile on buffer BI; when STG, stages tile KT2 into buffer (BI+2)%3.
// WAITN: 6 = steady state (tile BI's 6 loads done, newer 6 in flight);
//        0 = final drain.
#define DO_TILE(BI, KT2, STG, WAITN) do {                                     \
    WVM(WAITN);                                                               \
    BAR; SB0;                                                                 \
    if (STG) {   /* 6 async16: A 4 slices, B 2 slices, of tile KT2 */         \
        int8_t* dst = lds + (((BI) + 2) % 3) * BUFB;                          \
        const int kb = (KT2) * BK;                                            \
        async16(gA + kb,           dst + ldsOff);                             \
        async16(gA + 131072 + kb,  dst + 4096 + ldsOff);                      \
        async16(gA + 262144 + kb,  dst + 8192 + ldsOff);                      \
        async16(gA + 393216 + kb,  dst + 12288 + ldsOff);                     \
        async16(gB + kb,           dst + ATILE + ldsOff);                     \
        async16(gB + 131072 + kb,  dst + ATILE + 4096 + ldsOff);              \
    }                                                                         \
    SB0;                                                                      \
    {                                                                         \
        const int8_t* la = lds + (BI) * BUFB;                                 \
        const int8_t* lb = la + ATILE;                                        \
        bf[0] = *(const i32x4*)(lb + boff);                                   \
        bf[1] = *(const i32x4*)(lb + boff + 1024);                            \
        bf[2] = *(const i32x4*)(lb + boff + 2048);                            \
        bf[3] = *(const i32x4*)(lb + boff + 3072);                            \
        af[0] = *(const i32x4*)(la + aoff);                                   \
        SB0;                                                                  \
        af[1] = *(const i32x4*)(la + aoff + 1024);                            \
        af[2] = *(const i32x4*)(la + aoff + 2048);                            \
        SB0;                                                                  \
        __builtin_amdgcn_s_setprio(1);                                        \
        WLG(2); SB0; CL(0);                                                   \
        af[3] = *(const i32x4*)(la + aoff + 3072); SB0;                       \
        WLG(2); SB0; CL(1);                                                   \
        af[4] = *(const i32x4*)(la + aoff + 4096); SB0;                       \
        WLG(2); SB0; CL(2);                                                   \
        af[5] = *(const i32x4*)(la + aoff + 5120); SB0;                       \
        WLG(2); SB0; CL(3);                                                   \
        af[6] = *(const i32x4*)(la + aoff + 6144); SB0;                       \
        WLG(2); SB0; CL(4);                                                   \
        af[7] = *(const i32x4*)(la + aoff + 7168); SB0;                       \
        WLG(2); SB0; CL(5);                                                   \
        WLG(1); SB0; CL(6);                                                   \
        WLG(0); SB0; CL(7);                                                   \
        __builtin_amdgcn_s_setprio(0);                                        \
        SB0;                                                                  \
    }                                                                         \
} while (0)

// --- int8 GEMM: 256x128 tile, 4 waves, 3-buffer ring, 2 blocks/CU ---
__global__ __launch_bounds__(256, 2) void gemm_i8_kernel(const int8_t* __restrict__ A,
                                                         const int8_t* __restrict__ W,
                                                         const int* __restrict__ rowsum,
                                                         float* __restrict__ out) {
    extern __shared__ int8_t lds[];   // 3 * 24 KB

    // XCD-aware swizzle: 1024 wgs, 8 XCDs, 128 contiguous tiles per XCD
    int bid = blockIdx.x;
    int wg = (bid & 7) * 128 + (bid >> 3);
    int tm = wg >> 4;                 // 64 row tiles
    int tn = wg & 15;                 // 16 col tiles
    int brow = tm * BM;
    int bcol = tn * BN;

    int tid  = threadIdx.x;
    int lane = tid & 63;
    int wv   = tid >> 6;
    int wr = wv >> 1, wc = wv & 1;    // 2x2 waves, each 128x64 output
    int l15 = lane & 15;
    int kg  = lane >> 4;              // 0..3

    // staging: slice s covers rows s*64 + (tid>>2), chunk col tid&3.
    // LDS chunk (r,c) holds global chunk (r, c ^ ((r>>1)&3));
    // ((r>>1)&3) == ((tid>>3)&3) for all slices (s*64 even in r>>1 mod 4).
    int csw = (tid & 3) ^ ((tid >> 3) & 3);
    const int8_t* gA = A + (size_t)(brow + (tid >> 2)) * IN_DIM + csw * 16;
    const int8_t* gB = W + (size_t)(bcol + (tid >> 2)) * IN_DIM + csw * 16;
    const int ldsOff = tid * 16;      // within each 4 KB slice

    // ds_read: lane wants (row, k-chunk kg); swizzled chunk = kg^((row>>1)&3),
    // and (row>>1)&3 == (l15>>1)&3 for all fragments (m*16, wr*128, wc*64,
    // n*16 all even multiples of 8 in row>>1).
    const int koff = ((kg ^ ((l15 >> 1) & 3)) << 4);
    const int aoff = (wr * 128 + l15) * BK + koff;    // + m*1024
    const int boff = (wc * 64 + l15) * BK + koff;     // + n*1024

    i32x4 acc[8][4];
#pragma unroll
    for (int m = 0; m < 8; ++m)
#pragma unroll
        for (int n = 0; n < 4; ++n)
            acc[m][n] = (i32x4){0, 0, 0, 0};
    i32x4 af[8], bf[4];

    // ---- prologue: stage tiles 0,1 into buf0,buf1 (6 loads each) ----
    {
        async16(gA,          lds + ldsOff);
        async16(gA + 131072, lds + 4096 + ldsOff);
        async16(gA + 262144, lds + 8192 + ldsOff);
        async16(gA + 393216, lds + 12288 + ldsOff);
        async16(gB,          lds + ATILE + ldsOff);
        async16(gB + 131072, lds + ATILE + 4096 + ldsOff);
        async16(gA + BK,           lds + BUFB + ldsOff);
        async16(gA + 131072 + BK,  lds + BUFB + 4096 + ldsOff);
        async16(gA + 262144 + BK,  lds + BUFB + 8192 + ldsOff);
        async16(gA + 393216 + BK,  lds + BUFB + 12288 + ldsOff);
        async16(gB + BK,           lds + BUFB + ATILE + ldsOff);
        async16(gB + 131072 + BK,  lds + BUFB + ATILE + 4096 + ldsOff);
    }

    // ---- main loop: tiles 0..29 stage tiles 2..31; then 2 tail tiles ----
    int kt = 0;
#pragma unroll 1
    for (int t = 0; t < 10; ++t) {
        DO_TILE(0, kt + 2, 1, 6);
        DO_TILE(1, kt + 3, 1, 6);
        DO_TILE(2, kt + 4, 1, 6);
        kt += 3;
    }
    DO_TILE(0, 0, 0, 6);    // tile 30 (tile 31's 6 loads in flight)
    DO_TILE(1, 0, 0, 0);    // tile 31 (drain)

    // ---- epilogue: zero-point, scale, photodetect square, ReLUN(6) ----
    const float scale = (float)(2.0 / 32385.0);   // 2/(255*127)
#pragma unroll
    for (int n = 0; n < 4; ++n) {
        int col = bcol + wc * 64 + n * 16 + l15;
        int rs128 = rowsum[col] << 7;             // 128 * sum_k wi[col,k]
#pragma unroll
        for (int m = 0; m < 8; ++m) {
            int row0 = brow + wr * 128 + m * 16 + kg * 4;
#pragma unroll
            for (int r = 0; r < 4; ++r) {
                float f = (float)(acc[m][n][r] + rs128) * scale;
                f = f * f;
                f = fminf(f, 6.0f);
                out[(size_t)(row0 + r) * OUT_DIM + col] = f;
            }
        }
    }
}

extern "C" void kernel_launch(void* const* d_in, const int* in_sizes, int n_in,
                              void* d_out, int out_size, void* d_ws, size_t ws_size,
                              hipStream_t stream) {
    const float* x  = (const float*)d_in[0];   // [16384, 2048] f32
    const float* wt = (const float*)d_in[1];   // [256, 256, 8, 8] f32
    float* out = (float*)d_out;                // [16384, 2048] f32

    char* ws = (char*)d_ws;
    int8_t* xq = (int8_t*)ws;                                   // 32 MB
    int8_t* wq = (int8_t*)(ws + (size_t)B_DIM * IN_DIM);        // 4 MB
    int*    rowsum = (int*)(ws + (size_t)B_DIM * IN_DIM
                               + (size_t)OUT_DIM * IN_DIM);     // 8 KB

    hipMemsetAsync(rowsum, 0, OUT_DIM * sizeof(int), stream);
    quant_x_kernel<<<(B_DIM * IN_DIM / 16) / 256, 256, 0, stream>>>(x, xq);
    quant_w_kernel<<<256, 256, 0, stream>>>(wt, wq, rowsum);
    gemm_i8_kernel<<<(B_DIM / BM) * (OUT_DIM / BN), 256, 3 * BUFB, stream>>>(xq, wq, rowsum, out);
}

// Round 7
// 117.341 us; speedup vs baseline: 1.0604x; 1.0604x over previous
//
#include <hip/hip_runtime.h>
#include <stdint.h>

// ---------------------------------------------------------------------------
// LinearBlock: out[b, p*8+o] = clip((sum_{q,i} Wq[p,q,o,i]*xq[b,q*8+i])^2, 0, 6)
// Exact int8 path:
//   xq = xu/255,        xu = round(clip(x,0,1)*255)       in [0,255]
//   wq = wi*2/127,      wi = round(clip(w,-2,2)*63.5)     in [-127,127]
//   dot = (sum xu*wi) * 2/(255*127);  A zero-point: xs=xu-128, +128*rowsum[n].
//
// Round 7: TRUE T3+T4. 256x256, BK=128, 8 waves; wave output interleaved
// across halves (rows wr*64+mh*128, cols wc*32+nh*128) so each phase consumes
// exactly one A-half and one B-half. 4 phases/tile = quadrants (0,0),(0,1),
// (1,1),(1,0), reads 12/4/8/0. Staging 1 half/phase in consumption order
// {Aa,Ba,Bb,Ab} -> >=3-phase distance; counted vmcnt(4) at P0/P1/P2, NO
// drain in main loop. WVM->BAR->ds_reads ordering makes counted waits sound.
// ---------------------------------------------------------------------------

typedef int i32x4 __attribute__((ext_vector_type(4)));

#define B_DIM   16384
#define IN_DIM  2048
#define OUT_DIM 2048

#define BM 256
#define BN 256
#define BK 128
#define KTILES (IN_DIM / BK)   // 16
#define HALF   16384           // bytes per half-tile (128 rows x 128 B)
#define BUFB   (4 * HALF)      // 64 KB: [Aa][Ab][Ba][Bb]

__device__ __forceinline__ void async16(const void* g, void* l) {
    __builtin_amdgcn_global_load_lds(
        (const __attribute__((address_space(1))) void*)g,
        (__attribute__((address_space(3))) void*)l, 16, 0, 0);
}

// --- quantize x: float [B,IN] -> int8 (value-128) [B,IN], 16 elems/thread ---
__global__ __launch_bounds__(256) void quant_x_kernel(const float* __restrict__ x,
                                                      int8_t* __restrict__ xq) {
    int i = blockIdx.x * 256 + threadIdx.x;           // 16-elem chunk id
    const float4* xv = (const float4*)x + (size_t)i * 4;
    union { int8_t c[16]; i32x4 v; } u;
#pragma unroll
    for (int j = 0; j < 4; ++j) {
        float4 v = xv[j];
        float f[4] = {v.x, v.y, v.z, v.w};
#pragma unroll
        for (int e = 0; e < 4; ++e) {
            float c = fminf(fmaxf(f[e], 0.0f), 1.0f);
            int q = (int)rintf(c * 255.0f) - 128;
            u.c[j * 4 + e] = (int8_t)q;
        }
    }
    *((i32x4*)xq + i) = u.v;
}

// --- quantize + relayout weight: [P=256,Q=256,8,8] f32 -> [2048][2048] int8
__global__ __launch_bounds__(256) void quant_w_kernel(const float* __restrict__ w,
                                                      int8_t* __restrict__ wq,
                                                      int* __restrict__ rowsum) {
    int p = blockIdx.x;          // 0..255
    int t = threadIdx.x;         // 0..255
    const float* wp = w + (size_t)p * 16384;
    int n = p * 8 + (t & 7);
    int lsum = 0;
#pragma unroll
    for (int s = 0; s < 8; ++s) {
        int g = t + s * 256;                     // 8-elem group id, 0..2047
        float4 v0 = *(const float4*)(wp + g * 8);
        float4 v1 = *(const float4*)(wp + g * 8 + 4);
        float f[8] = {v0.x, v0.y, v0.z, v0.w, v1.x, v1.y, v1.z, v1.w};
        union { int8_t c[8]; long long ll; } u;
#pragma unroll
        for (int e = 0; e < 8; ++e) {
            float c = fminf(fmaxf(f[e], -2.0f), 2.0f);
            int q = (int)rintf(c * 63.5f);       // == round((w/2)*127), exact
            u.c[e] = (int8_t)q;
            lsum += q;
        }
        int kg = g >> 3;
        *(long long*)(wq + (size_t)n * 2048 + kg * 8) = u.ll;
    }
    atomicAdd(&rowsum[n], lsum);
}

#define SB0 __builtin_amdgcn_sched_barrier(0)
#define BAR __builtin_amdgcn_s_barrier()
#define WLG0 asm volatile("s_waitcnt lgkmcnt(0)" ::: "memory")
#define WVM(n) asm volatile("s_waitcnt vmcnt(" #n ")" ::: "memory")
#define LD(p) (*(const i32x4*)(p))

// 16 MFMA quadrant: acc[MH][NH] over mf(4) x nf(2) x kk(2)
#define CLPH(MH, NH, BF)                                                      \
    _Pragma("unroll")                                                         \
    for (int mf = 0; mf < 4; ++mf)                                            \
        _Pragma("unroll")                                                     \
        for (int nf = 0; nf < 2; ++nf)                                        \
            _Pragma("unroll")                                                 \
            for (int kk = 0; kk < 2; ++kk)                                    \
                acc[MH][NH][mf][nf] = __builtin_amdgcn_mfma_i32_16x16x64_i8(  \
                    af[2 * mf + kk], BF[2 * nf + kk], acc[MH][NH][mf][nf], 0, 0, 0);

#define RD_A(BASEOFF)                                                         \
    af[0] = LD(base + (BASEOFF) + aoff0);                                     \
    af[1] = LD(base + (BASEOFF) + (aoff0 ^ 64));                              \
    af[2] = LD(base + (BASEOFF) + aoff0 + 2048);                              \
    af[3] = LD(base + (BASEOFF) + ((aoff0 + 2048) ^ 64));                     \
    af[4] = LD(base + (BASEOFF) + aoff0 + 4096);                              \
    af[5] = LD(base + (BASEOFF) + ((aoff0 + 4096) ^ 64));                     \
    af[6] = LD(base + (BASEOFF) + aoff0 + 6144);                              \
    af[7] = LD(base + (BASEOFF) + ((aoff0 + 6144) ^ 64));

#define RD_B(BF, BASEOFF)                                                     \
    BF[0] = LD(base + (BASEOFF) + boff0);                                     \
    BF[1] = LD(base + (BASEOFF) + (boff0 ^ 64));                              \
    BF[2] = LD(base + (BASEOFF) + boff0 + 2048);                              \
    BF[3] = LD(base + (BASEOFF) + ((boff0 + 2048) ^ 64));

// One K-tile on buffer BB; when STG, stages tile KT2's halves (order
// Aa,Ba,Bb,Ab) into buffer BB^1. Waits: P0 vmcnt(4); P1 vmcnt(W1);
// P2 vmcnt(W2); P3 none. Steady (W1,W2)=(4,4); tail tile (2,0).
#define DO_TILE(BB, KT2, STG, W1, W2) do {                                    \
    const int8_t* base = lds + (BB) * BUFB;                                   \
    int8_t* dst = lds + ((BB) ^ 1) * BUFB;                                    \
    const int kb = (KT2) * BK;                                                \
    /* ---- P0: quad (mh0,nh0); reads Aa(8)+Ba(4); stage Aa' ---- */          \
    WVM(4); SB0; BAR;                                                         \
    RD_A(0)                                                                   \
    RD_B(bf0, 2 * HALF)                                                       \
    if (STG) { async16(gAa + kb, dst + t16);                                  \
               async16(gAa + 131072 + kb, dst + 8192 + t16); }                \
    SB0; WLG0; SB0;                                                           \
    __builtin_amdgcn_s_setprio(1);                                            \
    CLPH(0, 0, bf0)                                                           \
    __builtin_amdgcn_s_setprio(0); SB0;                                       \
    /* ---- P1: quad (mh0,nh1); reads Bb(4); stage Ba' ---- */                \
    WVM(W1); SB0; BAR;                                                        \
    RD_B(bf1, 3 * HALF)                                                       \
    if (STG) { async16(gBa + kb, dst + 2 * HALF + t16);                       \
               async16(gBa + 131072 + kb, dst + 2 * HALF + 8192 + t16); }     \
    SB0; WLG0; SB0;                                                           \
    __builtin_amdgcn_s_setprio(1);                                            \
    CLPH(0, 1, bf1)                                                           \
    __builtin_amdgcn_s_setprio(0); SB0;                                       \
    /* ---- P2: quad (mh1,nh1); reads Ab(8); stage Bb' ---- */                \
    WVM(W2); SB0; BAR;                                                        \
    RD_A(HALF)                                                                \
    if (STG) { async16(gBb + kb, dst + 3 * HALF + t16);                       \
               async16(gBb + 131072 + kb, dst + 3 * HALF + 8192 + t16); }     \
    SB0; WLG0; SB0;                                                           \
    __builtin_amdgcn_s_setprio(1);                                            \
    CLPH(1, 1, bf1)                                                           \
    __builtin_amdgcn_s_setprio(0); SB0;                                       \
    /* ---- P3: quad (mh1,nh0); no reads; stage Ab' ---- */                   \
    BAR;                                                                      \
    if (STG) { async16(gAb + kb, dst + HALF + t16);                           \
               async16(gAb + 131072 + kb, dst + HALF + 8192 + t16); }         \
    SB0;                                                                      \
    __builtin_amdgcn_s_setprio(1);                                            \
    CLPH(1, 0, bf0)                                                           \
    __builtin_amdgcn_s_setprio(0); SB0;                                       \
} while (0)

// --- int8 GEMM: 256x256, BK=128, 8 waves, dbuf, counted-vmcnt 4-phase ---
__global__ __launch_bounds__(512, 2) void gemm_i8_kernel(const int8_t* __restrict__ A,
                                                         const int8_t* __restrict__ W,
                                                         const int* __restrict__ rowsum,
                                                         float* __restrict__ out) {
    extern __shared__ int8_t lds[];   // 2 * 64 KB

    // XCD-aware swizzle: 512 wgs, 8 XCDs, 64 contiguous tiles per XCD
    int bid = blockIdx.x;
    int wg = (bid & 7) * 64 + (bid >> 3);
    int tm = wg >> 3;                 // 64 row tiles
    int tn = wg & 7;                  // 8 col tiles
    int brow = tm * BM;
    int bcol = tn * BN;

    int tid  = threadIdx.x;
    int lane = tid & 63;
    int wv   = tid >> 6;
    int wr = wv >> 2, wc = wv & 3;    // 2x4 waves
    int l15 = lane & 15;
    int kg  = lane >> 4;              // 0..3

    // staging: per half (128 rows x 8 chunks), thread t covers rows t>>3 and
    // 64+(t>>3), chunk col t&7, swizzled: LDS (rl,c) holds global
    // (rl, c ^ ((rl>>1)&7)); ((rl>>1)&7) == (t>>4)&7 for both slices.
    int csw = (tid & 7) ^ ((tid >> 4) & 7);
    const int8_t* gAa = A + (size_t)(brow + (tid >> 3)) * IN_DIM + csw * 16;
    const int8_t* gAb = gAa + 128 * IN_DIM;
    const int8_t* gBa = W + (size_t)(bcol + (tid >> 3)) * IN_DIM + csw * 16;
    const int8_t* gBb = gBa + 128 * IN_DIM;
    const int t16 = tid * 16;

    // reads: A half-local row rl = wr*64 + mf*16 + l15; B rl = wc*32+nf*16+l15;
    // chunk kc = kk*4+kg, swizzled kc^((rl>>1)&7), (rl>>1)&7 == (l15>>1)&7.
    const int xsw   = (l15 >> 1) & 7;
    const int koff0 = ((kg ^ xsw) << 4);          // kk=0; kk=1 is ^64
    const int aoff0 = (wr * 64 + l15) * BK + koff0;   // + mf*2048
    const int boff0 = (wc * 32 + l15) * BK + koff0;   // + nf*2048

    i32x4 acc[2][2][4][2];
#pragma unroll
    for (int mh = 0; mh < 2; ++mh)
#pragma unroll
        for (int nh = 0; nh < 2; ++nh)
#pragma unroll
            for (int mf = 0; mf < 4; ++mf)
#pragma unroll
                for (int nf = 0; nf < 2; ++nf)
                    acc[mh][nh][mf][nf] = (i32x4){0, 0, 0, 0};
    i32x4 af[8], bf0[4], bf1[4];

    // ---- prologue: stage tile 0's halves in ledger order Aa,Ba,Bb,Ab ----
    async16(gAa, lds + t16);
    async16(gAa + 131072, lds + 8192 + t16);
    async16(gBa, lds + 2 * HALF + t16);
    async16(gBa + 131072, lds + 2 * HALF + 8192 + t16);
    async16(gBb, lds + 3 * HALF + t16);
    async16(gBb + 131072, lds + 3 * HALF + 8192 + t16);
    async16(gAb, lds + HALF + t16);
    async16(gAb + 131072, lds + HALF + 8192 + t16);

    // ---- main loop: 16 K-tiles, tile T (buf T&1) stages T+1 ----
#pragma unroll 1
    for (int i = 0; i < 7; ++i) {
        DO_TILE(0, 2 * i + 1, 1, 4, 4);
        DO_TILE(1, 2 * i + 2, 1, 4, 4);
    }
    DO_TILE(0, 15, 1, 4, 4);
    DO_TILE(1, 0, 0, 2, 0);   // tail: counted 2, then drain 0 (last tile only)

    // ---- epilogue: zero-point, scale, photodetect square, ReLUN(6) ----
    const float scale = (float)(2.0 / 32385.0);   // 2/(255*127)
#pragma unroll
    for (int nh = 0; nh < 2; ++nh)
#pragma unroll
        for (int nf = 0; nf < 2; ++nf) {
            int col = bcol + nh * 128 + wc * 32 + nf * 16 + l15;
            int rs128 = rowsum[col] << 7;         // 128 * sum_k wi[col,k]
#pragma unroll
            for (int mh = 0; mh < 2; ++mh)
#pragma unroll
                for (int mf = 0; mf < 4; ++mf) {
                    int row0 = brow + mh * 128 + wr * 64 + mf * 16 + kg * 4;
#pragma unroll
                    for (int r = 0; r < 4; ++r) {
                        float f = (float)(acc[mh][nh][mf][nf][r] + rs128) * scale;
                        f = f * f;
                        f = fminf(f, 6.0f);
                        out[(size_t)(row0 + r) * OUT_DIM + col] = f;
                    }
                }
        }
}

extern "C" void kernel_launch(void* const* d_in, const int* in_sizes, int n_in,
                              void* d_out, int out_size, void* d_ws, size_t ws_size,
                              hipStream_t stream) {
    const float* x  = (const float*)d_in[0];   // [16384, 2048] f32
    const float* wt = (const float*)d_in[1];   // [256, 256, 8, 8] f32
    float* out = (float*)d_out;                // [16384, 2048] f32

    char* ws = (char*)d_ws;
    int8_t* xq = (int8_t*)ws;                                   // 32 MB
    int8_t* wq = (int8_t*)(ws + (size_t)B_DIM * IN_DIM);        // 4 MB
    int*    rowsum = (int*)(ws + (size_t)B_DIM * IN_DIM
                               + (size_t)OUT_DIM * IN_DIM);     // 8 KB

    hipMemsetAsync(rowsum, 0, OUT_DIM * sizeof(int), stream);
    quant_x_kernel<<<(B_DIM * IN_DIM / 16) / 256, 256, 0, stream>>>(x, xq);
    quant_w_kernel<<<256, 256, 0, stream>>>(wt, wq, rowsum);
    gemm_i8_kernel<<<(B_DIM / BM) * (OUT_DIM / BN), 512, 2 * BUFB, stream>>>(xq, wq, rowsum, out);
}